// Round 3
// baseline (298.903 us; speedup 1.0000x reference)
//
#include <hip/hip_runtime.h>
#include <math.h>

#define N 1024
#define E 32
#define L 8
#define NN ((size_t)N * N)

using short8 = __attribute__((ext_vector_type(8))) short;
using f32x4v = __attribute__((ext_vector_type(4))) float;

// split fp32 into bf16 hi + bf16 lo (truncation; residual ~2^-16 relative)
__device__ inline ushort2 split_bf16(float v) {
  unsigned ui = __float_as_uint(v);
  ushort h = (ushort)(ui >> 16);
  float hv = __uint_as_float((unsigned)h << 16);
  float r = v - hv;
  ushort l = (ushort)(__float_as_uint(r) >> 16);
  return make_ushort2(h, l);
}

// ---------------- kernel 1: fused wv + P-transpose + tail ----------------
// blocks [0, 8192): wv path, round-1 layout (8 lanes/row, 4 rows/thread):
//   dense per-instruction coalescing (1 KB/instr), VGPR 20, measured 81 us.
// blocks [8192, 8448): Pt[i][j] = att_stack[j,i,:].ptr (transposed, hi/lo)
// block 8448: out tail
__global__ __launch_bounds__(256) void k_prep(
    const float* __restrict__ feat, const float* __restrict__ fe,
    const float* __restrict__ mono, const float* __restrict__ cm,
    const float* __restrict__ c_i, const float* __restrict__ w_c,
    const float* __restrict__ b_c,
    const float* __restrict__ att_stack, const float* __restrict__ ptr,
    ushort* __restrict__ wv_h, ushort* __restrict__ wv_l,
    ushort* __restrict__ Pt_h, ushort* __restrict__ Pt_l,
    float* __restrict__ out_tail) {
  __shared__ __align__(16) float qsm[32];
  __shared__ ushort Ts[2][64][66];   // pad 66: conflict-free column writes
  int tid = threadIdx.x;
  int b = blockIdx.x;
  if (b < 8192) {
    // ---- wv path (coalesced, 8 lanes/row, 4 rows/thread) ----
    int seg = tid & 7;
    int rl = tid >> 3;             // 0..31 local row
    bool qblock = (b < 8);         // gid < 1024 <=> m == 0
    if (qblock) {                  // compute query cooperatively
      int e = tid >> 3, r = tid & 7;
      float s = 0.f;
      for (int h = r; h < N; h += 8) s += c_i[h] * w_c[e * N + h];
      s += __shfl_down(s, 4, 8);
      s += __shfl_down(s, 2, 8);
      s += __shfl_down(s, 1, 8);
      if (r == 0) qsm[e] = s + b_c[e];
      __syncthreads();
    }
    float4 c = *(const float4*)(cm + seg * 4);
    float4 qa;
    if (qblock) qa = *((const float4*)qsm + seg);
    #pragma unroll
    for (int it = 0; it < 4; ++it) {
      int gid = b * 128 + it * 32 + rl;   // m*N + y
      int m = gid >> 10;
      int y = gid & (N - 1);
      float4 a;
      if (qblock) {
        a = qa;
      } else {
        a = *(const float4*)(feat + ((size_t)(m - 1) * N + y) * E + seg * 4);
      }
      float4 f = *(const float4*)(fe + (size_t)y * E + seg * 4);
      float dx = a.x - f.x, dy = a.y - f.y, dz = a.z - f.z, dw = a.w - f.w;
      float s = c.x * (fmaxf(a.x + f.x, 0.f) - dx * dx)
              + c.y * (fmaxf(a.y + f.y, 0.f) - dy * dy)
              + c.z * (fmaxf(a.z + f.z, 0.f) - dz * dz)
              + c.w * (fmaxf(a.w + f.w, 0.f) - dw * dw);
      s += __shfl_down(s, 4, 8);
      s += __shfl_down(s, 2, 8);
      s += __shfl_down(s, 1, 8);
      if (seg == 0) {
        float v = mono[gid] * s;
        ushort2 hl = split_bf16(v);
        wv_h[gid] = hl.x;
        wv_l[gid] = hl.y;
      }
    }
  } else if (b < 8448) {
    // ---- P-transpose path ----
    int b2 = b - 8192;
    int j0 = (b2 >> 4) * 64;          // k-dim of Pt
    int i0 = (b2 & 15) * 64;          // x-dim of Pt
    float p0 = ptr[0], p1 = ptr[1], p2 = ptr[2], p3 = ptr[3];
    float p4 = ptr[4], p5 = ptr[5], p6 = ptr[6], p7 = ptr[7];
    int w = tid >> 6, lane = tid & 63;
    #pragma unroll 4
    for (int r = 0; r < 16; ++r) {
      int jl = r * 4 + w;
      int il = lane;
      const float4* a =
          (const float4*)(att_stack + ((size_t)(j0 + jl) * N + i0 + il) * L);
      float4 a0 = a[0], a1 = a[1];
      float s = a0.x * p0 + a0.y * p1 + a0.z * p2 + a0.w * p3
              + a1.x * p4 + a1.y * p5 + a1.z * p6 + a1.w * p7;
      ushort2 hl = split_bf16(s);
      Ts[0][il][jl] = hl.x;
      Ts[1][il][jl] = hl.y;
    }
    __syncthreads();
    int il = tid >> 2, cc = tid & 3;
    size_t o = (size_t)(i0 + il) * N + j0 + cc * 16;
    {
      const uint* sp = (const uint*)&Ts[0][il][cc * 16];
      uint4 d0 = {sp[0], sp[1], sp[2], sp[3]};
      uint4 d1 = {sp[4], sp[5], sp[6], sp[7]};
      *(uint4*)&Pt_h[o] = d0;
      *(uint4*)&Pt_h[o + 8] = d1;
    }
    {
      const uint* sp = (const uint*)&Ts[1][il][cc * 16];
      uint4 d0 = {sp[0], sp[1], sp[2], sp[3]};
      uint4 d1 = {sp[4], sp[5], sp[6], sp[7]};
      *(uint4*)&Pt_l[o] = d0;
      *(uint4*)&Pt_l[o + 8] = d1;
    }
  } else {
    // ---- output tail ----
    if (tid < 8) out_tail[tid] = ptr[tid];
    for (int i = tid; i < N; i += 256) out_tail[8 + i] = 0.f;
  }
}

// ---------------- kernel 2: MFMA matmul, direct-global reg pipeline ------
// C[x,m] = sum_k Pt[x][k] * wv[m][k], bf16 hi/lo (3 products).
// 64x64 tile, BK=32, K=1024; grid (16,16) = 256 blocks (1 block/CU).
// NO LDS staging, NO main-loop barriers: operand fragments load directly
// global->VGPR with a 4-deep register pipeline (stage = kt&3, full unroll
// -> static indexing). The compiler emits counted vmcnt waits 4 stages
// back (~930 cyc cover > L3 latency); no vmcnt(0) drain anywhere in the
// loop. B-fragment addresses are identical across the 4 waves -> L1
// broadcast; A rows are wave-private.
// Fragment lane mapping (matches the verified LDS-path layout):
//   A/B: row = base + (lane&15), k = kt*32 + (lane>>4)*8 .. +7
//   C/D: col = lane&15, row = (lane>>4)*4 + reg   [m89-verified]
__global__ __launch_bounds__(256) void k_mm(
    const ushort* __restrict__ Pt_h, const ushort* __restrict__ Pt_l,
    const ushort* __restrict__ wv_h, const ushort* __restrict__ wv_l,
    float* __restrict__ C, float* __restrict__ normp) {
  __shared__ float nm[64][17];
  int tid = threadIdx.x;
  int lane = tid & 63, w = tid >> 6;
  int x0 = blockIdx.x * 64, m0 = blockIdx.y * 64;
  int fr = lane & 15;          // row-in-16
  int fk = (lane >> 4) * 8;    // k-granule offset
  const ushort* pAh = Pt_h + (size_t)(x0 + w * 16 + fr) * N + fk;
  const ushort* pAl = Pt_l + (size_t)(x0 + w * 16 + fr) * N + fk;
  size_t br0 = (size_t)(m0 + 0 * 16 + fr) * N + fk;
  size_t br1 = (size_t)(m0 + 1 * 16 + fr) * N + fk;
  size_t br2 = (size_t)(m0 + 2 * 16 + fr) * N + fk;
  size_t br3 = (size_t)(m0 + 3 * 16 + fr) * N + fk;

  short8 Ah[4], Al[4], Bh[4][4], Bl[4][4];

#define LOADK(s, kt)                                                   \
  do {                                                                 \
    const int ko = (kt) * 32;                                          \
    Ah[s] = *(const short8*)(pAh + ko);                                \
    Al[s] = *(const short8*)(pAl + ko);                                \
    Bh[s][0] = *(const short8*)(wv_h + br0 + ko);                      \
    Bl[s][0] = *(const short8*)(wv_l + br0 + ko);                      \
    Bh[s][1] = *(const short8*)(wv_h + br1 + ko);                      \
    Bl[s][1] = *(const short8*)(wv_l + br1 + ko);                      \
    Bh[s][2] = *(const short8*)(wv_h + br2 + ko);                      \
    Bl[s][2] = *(const short8*)(wv_l + br2 + ko);                      \
    Bh[s][3] = *(const short8*)(wv_h + br3 + ko);                      \
    Bl[s][3] = *(const short8*)(wv_l + br3 + ko);                      \
  } while (0)

  f32x4v acc[4];
  #pragma unroll
  for (int t = 0; t < 4; ++t) acc[t] = (f32x4v){0.f, 0.f, 0.f, 0.f};

  LOADK(0, 0);
  LOADK(1, 1);
  LOADK(2, 2);
  LOADK(3, 3);

  #pragma unroll
  for (int kt = 0; kt < 32; ++kt) {
    const int s = kt & 3;
    #pragma unroll
    for (int t = 0; t < 4; ++t) {
      acc[t] = __builtin_amdgcn_mfma_f32_16x16x32_bf16(Ah[s], Bh[s][t], acc[t], 0, 0, 0);
      acc[t] = __builtin_amdgcn_mfma_f32_16x16x32_bf16(Ah[s], Bl[s][t], acc[t], 0, 0, 0);
      acc[t] = __builtin_amdgcn_mfma_f32_16x16x32_bf16(Al[s], Bh[s][t], acc[t], 0, 0, 0);
    }
    if (kt < 28) LOADK(s, kt + 4);
  }
#undef LOADK

  // C/D layout: col = lane&15, row = (lane>>4)*4 + reg  [m89-verified]
  int orow = x0 + w * 16 + (lane >> 4) * 4;
  int ocol = m0 + fr;
  int cidx = w * 4 + (lane >> 4);    // 16 contributors per m-column
  #pragma unroll
  for (int t = 0; t < 4; ++t) {
    float mx = -INFINITY;
    #pragma unroll
    for (int r = 0; r < 4; ++r) {
      float v = acc[t][r];
      C[(size_t)(orow + r) * N + ocol + t * 16] = v;
      mx = fmaxf(mx, v);
    }
    nm[t * 16 + fr][cidx] = mx;
  }
  __syncthreads();
  if (tid < 64) {
    float mx = nm[tid][0];
    #pragma unroll
    for (int j = 1; j < 16; ++j) mx = fmaxf(mx, nm[tid][j]);
    normp[(size_t)blockIdx.x * N + m0 + tid] = mx;
  }
}

// ---------------- kernel 3: fused norm-finish + blend --------------------
// One float4 per thread (f = gid*2 + half): att_stack/out accesses are
// perfectly dense 16 B/lane (was 32 B-strided). normp (64 KB) L2-resident.
__global__ __launch_bounds__(256) void k_fin(
    const float* __restrict__ C, const float* __restrict__ normp,
    const float* __restrict__ att_stack, const float* __restrict__ ptr,
    float* __restrict__ out) {
  int f = blockIdx.x * 256 + threadIdx.x;   // float4 index in [0, 2*N*N)
  int gid = f >> 1;                         // x*N + m
  int m = gid & (N - 1);
  int h = f & 1;
  float mx = normp[m];
  #pragma unroll
  for (int xg = 1; xg < 16; ++xg)
    mx = fmaxf(mx, normp[(size_t)xg * N + m]);
  float nrm = (mx <= 1.f) ? 1.f : mx;
  float a = C[gid] / nrm;
  float4 s0 = ((const float4*)att_stack)[f];
  float4 p = ((const float4*)ptr)[h];
  float4 o0;
  o0.x = a * p.x + s0.x * (1.f - p.x);
  o0.y = a * p.y + s0.y * (1.f - p.y);
  o0.z = a * p.z + s0.z * (1.f - p.z);
  o0.w = a * p.w + s0.w * (1.f - p.w);
  ((float4*)out)[f] = o0;
}

extern "C" void kernel_launch(void* const* d_in, const int* in_sizes, int n_in,
                              void* d_out, int out_size, void* d_ws, size_t ws_size,
                              hipStream_t stream) {
  const float* feat      = (const float*)d_in[1];
  const float* feat_edge = (const float*)d_in[2];
  const float* c_i       = (const float*)d_in[3];
  const float* att_stack = (const float*)d_in[5];
  const float* stack_ptr = (const float*)d_in[6];
  const float* mono_mask = (const float*)d_in[8];
  const float* cross_mask= (const float*)d_in[9];
  const float* w_c       = (const float*)d_in[10];
  const float* b_c       = (const float*)d_in[11];

  float* out = (float*)d_out;

  // ws layout: 4 ushort planes (8 MB), C (4 MB), normp (64 KB)
  ushort* wv_h = (ushort*)d_ws;
  ushort* wv_l = wv_h + NN;
  ushort* Pt_h = wv_l + NN;
  ushort* Pt_l = Pt_h + NN;
  float*  C    = (float*)(Pt_l + NN);
  float*  normp= C + NN;               // 16*N

  float* out_tail = out + NN * L;      // stack_ptr + mem zeros

  k_prep<<<8449, 256, 0, stream>>>(feat, feat_edge, mono_mask, cross_mask,
                                   c_i, w_c, b_c, att_stack, stack_ptr,
                                   wv_h, wv_l, Pt_h, Pt_l, out_tail);
  dim3 mmgrid(16, 16);
  k_mm<<<mmgrid, 256, 0, stream>>>(Pt_h, Pt_l, wv_h, wv_l, C, normp);
  k_fin<<<8192, 256, 0, stream>>>(C, normp, att_stack, stack_ptr, out);
}